// Round 13
// baseline (195.470 us; speedup 1.0000x reference)
//
#include <hip/hip_runtime.h>

#define BATCH 4096
#define N 64

// One DPP unsigned-max step: x = max(x, dpp_move(x)). VALU only.
template<int CTRL>
__device__ __forceinline__ unsigned dpp_umax(unsigned x) {
    unsigned moved = (unsigned)__builtin_amdgcn_update_dpp(0, (int)x, CTRL, 0xf, 0xf, true);
    return (moved > x) ? moved : x;
}

// Broadcast float from wave-uniform lane ps via v_readlane (SGPR result).
__device__ __forceinline__ float lanebcastf(float v, int ps) {
    return __uint_as_float(__builtin_amdgcn_readlane(__float_as_uint(v), ps));
}

// Packed-key argmax over live lanes: key = (bits(|col|) & ~63) | lane is
// monotone in |col| for floats >= 0 -> one umax tree + one readlane yields
// max AND pivot lane (wave-uniform).
__device__ __forceinline__ int pivot_argmax(float col, bool alive, int lane) {
    unsigned t = (__float_as_uint(col) & 0x7FFFFFC0u) | (unsigned)lane;
    unsigned r = alive ? t : 0u;
    r = dpp_umax<0x111>(r);   // row_shr:1
    r = dpp_umax<0x112>(r);   // row_shr:2
    r = dpp_umax<0x114>(r);   // row_shr:4
    r = dpp_umax<0x118>(r);   // row_shr:8
    r = dpp_umax<0x142>(r);   // row_bcast:15
    r = dpp_umax<0x143>(r);   // row_bcast:31
    return (int)(((unsigned)__builtin_amdgcn_readlane((int)r, 63)) & 63u);
}

// One IN-PLACE elimination step with shift renaming: pivot column is a[0];
// updates written shifted (a[j-1] = a[j] - m*u_j) so next pivot col is a[0].
// The broadcast stream is SOFTWARE-PIPELINED by one element: readlane(j+1)
// issues before the fma consuming u_j -> two live broadcast values force
// distinct SGPRs and make every readlane independent of the adjacent fma
// (round-13 probe: distinguishes readlane hazard-serialization from hard
// readlane throughput; rounds 3-12 excluded VGPR count, occupancy, code
// size, and per-wave chain length as the limiter).
template<int W>
__device__ __forceinline__ void lu_step(float (&a)[N],
                                        int &ps, bool &alive,
                                        unsigned long long &chosen, int &inv,
                                        unsigned &sbits, float &l2sum,
                                        int lane)
{
    // bookkeeping for the current pivot (column a[0], lane ps)
    inv += __popcll(chosen >> ps);
    chosen |= (1ull << ps);
    alive = alive && (lane != ps);

    const float pv = lanebcastf(a[0], ps);
    sbits ^= __float_as_uint(pv) & 0x80000000u;
    l2sum += __log2f(__builtin_fabsf(pv));

    // dead/pivot lanes free-run on garbage; safe: each pivot-row elem is
    // readlane'd before its owner's fma overwrites it, and dead rows are
    // never selected again.
    const float m = a[0] * __builtin_amdgcn_rcpf(pv);

    // lookahead: produce next pivot column a[0] first, start its argmax
    const float u1 = lanebcastf(a[1], ps);
    a[0] = __builtin_fmaf(-m, u1, a[1]);
    const int ps_next = pivot_argmax(a[0], alive, lane);

    // pipelined bulk trailing update (cols 2..W), one broadcast ahead
    float ucur = lanebcastf(a[2], ps);
    #pragma unroll
    for (int j = 2; j < W; ++j) {
        const float unext = lanebcastf(a[j + 1], ps);  // independent of fma(j)
        a[j - 1] = __builtin_fmaf(-m, ucur, a[j]);
        ucur = unext;
    }
    a[W - 1] = __builtin_fmaf(-m, ucur, a[W]);

    ps = ps_next;
}

// 16 steps at fixed compile-time width W, ROLLED. Static ~1 step-body.
template<int W>
__device__ __forceinline__ void lu_block16(float (&a)[N],
                                           int &ps, bool &alive,
                                           unsigned long long &chosen, int &inv,
                                           unsigned &sbits, float &l2sum,
                                           int lane)
{
    #pragma unroll 1
    for (int t = 0; t < 16; ++t) {
        lu_step<W>(a, ps, alive, chosen, inv, sbits, l2sum, lane);
    }
}

// Rolled + in-place (single a[64], ~90-reg working set) + waves_per_eu(1,2)
// (the only config that produced high arch-VGPR allocation, r6).
__global__ __launch_bounds__(64)
__attribute__((amdgpu_waves_per_eu(1, 2)))
void restricted_det_kernel(
    const float* __restrict__ U,
    const int* __restrict__ idx_up,
    const int* __restrict__ idx_dn,
    float* __restrict__ out)
{
    const int lane = threadIdx.x;      // 0..63, one wave per block
    const int wid  = blockIdx.x;       // sample id

    const int site0 = idx_up[wid * N + lane];
    const int site1 = idx_dn[wid * N + lane];

    float l2sum = 0.0f;                // sum log2|pivot| over both dets
    unsigned sbits = 0u;               // xor of pivot sign bits (uniform)
    int inv = 0;                       // inversion count (uniform)

    #pragma unroll 1
    for (int spin = 0; spin < 2; ++spin) {
        const int site = (spin == 0) ? site0 : site1;

        // lane i holds row i of the gathered matrix, in registers
        float a[N];
        {
            const float4* __restrict__ row =
                reinterpret_cast<const float4*>(U + (long)site * N);
            #pragma unroll
            for (int q = 0; q < N / 4; ++q) {
                float4 v = row[q];
                a[4*q+0]=v.x; a[4*q+1]=v.y; a[4*q+2]=v.z; a[4*q+3]=v.w;
            }
        }

        unsigned long long chosen = 0ull;
        bool alive = true;

        // prologue: pivot for step 0
        int ps = pivot_argmax(a[0], alive, lane);

        // 64 steps = 4 rolled blocks of 16; live width shrinks by 1 per
        // step (shift renaming), treated width per block: 63/47/31/15.
        // Updates past the live width hit garbage that is never read.
        lu_block16<63>(a, ps, alive, chosen, inv, sbits, l2sum, lane);
        lu_block16<47>(a, ps, alive, chosen, inv, sbits, l2sum, lane);
        lu_block16<31>(a, ps, alive, chosen, inv, sbits, l2sum, lane);
        lu_block16<15>(a, ps, alive, chosen, inv, sbits, l2sum, lane);
    }

    if (lane == 0) {
        const float sgn =
            (((sbits >> 31) ^ ((unsigned)inv & 1u)) != 0u) ? -1.0f : 1.0f;
        out[wid] = sgn;                                        // sign_up * sign_dn
        out[BATCH + wid] = l2sum * 0.69314718055994530942f;    // ln from log2
    }
}

extern "C" void kernel_launch(void* const* d_in, const int* in_sizes, int n_in,
                              void* d_out, int out_size, void* d_ws, size_t ws_size,
                              hipStream_t stream) {
    const float* U      = (const float*)d_in[0];
    const int*   idx_up = (const int*)d_in[1];
    const int*   idx_dn = (const int*)d_in[2];
    float* out = (float*)d_out;

    dim3 block(64);                  // one wave per block, 1 sample per wave
    dim3 grid(BATCH);                // 4096 waves, exact cover
    hipLaunchKernelGGL(restricted_det_kernel, grid, block, 0, stream,
                       U, idx_up, idx_dn, out);
}